// Round 5
// baseline (274.091 us; speedup 1.0000x reference)
//
#include <hip/hip_runtime.h>
#include <math.h>

#define B_ 2
#define N_ 6
#define D_ 59
#define FH 32
#define FW 88
#define C_ 80
#define NX 360
#define NY 360
#define P_PER_B (N_*D_*FH*FW)     // 996,864
#define NPTS (B_*P_PER_B)         // 1,993,728 = 7788*256
#define NCELL (NX*NY)             // 129,600
#define NC (B_*NCELL)             // 259,200 cells
#define NBLK 254                  // scan blocks (254*1024 = 260,096 >= NC)
#define NCP (NBLK*1024)           // padded cells
#define OUT4 (B_*C_*NCELL/4)      // 20,736,000 floats -> 5,184,000 float4
#define SUB 16                    // points per gather slot

// Static device scratch; every read location rewritten each launch (replay safe).
__device__ float g_inv[B_*N_*16];
__device__ int   g_code[NPTS];              // cell id or -1
__device__ __align__(16) int g_cnt[NCP];    // per-cell counts
__device__ int   g_desc[NBLK];              // lookback descriptors (status<<28|val)
__device__ int   g_offs[NC+1];              // global exclusive offsets (+ total)
__device__ int   g_cur[NC];                 // fill cursors
__device__ __align__(16) int g_plist[NPTS]; // cell-sorted point ids
__device__ __align__(16) int g_clist[NPTS]; // cell id per sorted position

// ---- 1) prep: zero counts + descriptors, invert the 12 matrices (block 0)
__global__ void k_prep(const float* __restrict__ l2i) {
  int i = blockIdx.x*256 + threadIdx.x;     // 254*256 = 65,024 int4 = NCP ints
  ((int4*)g_cnt)[i] = make_int4(0,0,0,0);
  if (i < NBLK) g_desc[i] = 0;
  if (blockIdx.x == 1 && threadIdx.x < B_*N_) {
    int m = threadIdx.x;
    double a[4][4], inv[4][4];
    for (int r=0;r<4;r++) for (int j=0;j<4;j++){
      a[r][j] = (double)l2i[m*16+r*4+j];
      inv[r][j] = (r==j)?1.0:0.0;
    }
    for (int k=0;k<4;k++){
      int p=k; double mx=fabs(a[k][k]);
      for (int r=k+1;r<4;r++){ double v=fabs(a[r][k]); if (v>mx){mx=v;p=r;} }
      if (p!=k){
        for (int j=0;j<4;j++){
          double t=a[k][j]; a[k][j]=a[p][j]; a[p][j]=t;
          t=inv[k][j]; inv[k][j]=inv[p][j]; inv[p][j]=t;
        }
      }
      double pi = 1.0/a[k][k];
      for (int j=0;j<4;j++){ a[k][j]*=pi; inv[k][j]*=pi; }
      for (int r=0;r<4;r++) if (r!=k){
        double f=a[r][k];
        for (int j=0;j<4;j++){ a[r][j]-=f*a[k][j]; inv[r][j]-=f*inv[k][j]; }
      }
    }
    for (int r=0;r<4;r++) for (int j=0;j<4;j++)
      g_inv[m*16+r*4+j] = (float)inv[r][j];
  }
}

// ---- 2) geometry -> code + wave-collapsed counts, FUSED with out zeroing
__global__ void k_geomz(const float* __restrict__ itrans, const float* __restrict__ iscale,
                        float* __restrict__ out) {
#pragma clang fp contract(off)
  int p = blockIdx.x*256 + threadIdx.x;     // grid exact: NPTS/256
  // fused zero of d_out (independent stream stores, overlaps with compute)
  for (int u = p; u < OUT4; u += NPTS)
    ((float4*)out)[u] = make_float4(0.f,0.f,0.f,0.f);

  int b  = p / P_PER_B;
  int r  = p - b*P_PER_B;
  int n  = r / (D_*FH*FW);
  int r2 = r - n*(D_*FH*FW);
  int d  = r2 / (FH*FW);
  int r3 = r2 - d*(FH*FW);
  int h  = r3 / FW;
  int w  = r3 - h*FW;
  int bn = b*N_ + n;

  float xw = (float)((double)w * (703.0/87.0));   // np.linspace in f64, rounded
  float yh = (float)((double)h * (255.0/31.0));
  float dd = (float)(d + 1);                      // ds = 1..59

  float t0 = itrans[bn*3+0], t1 = itrans[bn*3+1], t2 = itrans[bn*3+2];
  float s  = iscale[bn];

  float px = xw + t0, py = yh + t1, pd = dd + t2;
  float x0 = px / s, x1 = py / s;
  float p0 = x0*pd, p1 = x1*pd, p2 = pd;

  const float* iv = &g_inv[bn*16];
  float gx = ((iv[0]*p0 + iv[1]*p1) + iv[2]*p2)  + iv[3]*1.0f;
  float gy = ((iv[4]*p0 + iv[5]*p1) + iv[6]*p2)  + iv[7]*1.0f;
  float gz = ((iv[8]*p0 + iv[9]*p1) + iv[10]*p2) + iv[11]*1.0f;

  int vx = (int)((gx + 54.0f) / 0.3f);            // trunc == astype(int32)
  int vy = (int)((gy + 54.0f) / 0.3f);
  int vz = (int)((gz + 10.0f) / 20.0f);

  bool ok = (vx>=0) & (vx<NX) & (vy>=0) & (vy<NY) & (vz>=0) & (vz<1);
  int code = ok ? (b*NCELL + vx*NY + vy) : -1;
  g_code[p] = code;

  int lane = threadIdx.x & 63;
  int prev = __shfl_up(code, 1);
  bool leader = (lane == 0) || (code != prev);
  unsigned long long m = __ballot(leader);
  if (leader && code >= 0) {
    unsigned long long above = (lane < 63) ? (m >> (lane+1)) : 0ULL;
    int len = above ? __ffsll(above) : (64 - lane);
    atomicAdd(&g_cnt[code], len);
  }
}

// ---- 3) one-pass exclusive scan (decoupled lookback), writes offs+cur+total
__global__ void __launch_bounds__(1024) k_scan() {
  __shared__ int sd[1024];
  __shared__ int spfx;
  int t = threadIdx.x;
  int bi = blockIdx.x;
  int i = bi*1024 + t;
  int v = g_cnt[i];
  sd[t] = v;
  for (int off=1; off<1024; off<<=1) {
    __syncthreads();
    int x = (t >= off) ? sd[t-off] : 0;
    __syncthreads();
    sd[t] += x;
  }
  __syncthreads();
  int A = sd[1023];                       // block aggregate
  if (t == 0) {
    if (bi == 0) {
      __hip_atomic_store(&g_desc[0], (2<<28)|A, __ATOMIC_RELEASE, __HIP_MEMORY_SCOPE_AGENT);
      spfx = 0;
    } else {
      __hip_atomic_store(&g_desc[bi], (1<<28)|A, __ATOMIC_RELEASE, __HIP_MEMORY_SCOPE_AGENT);
      int run = 0, j = bi - 1;
      while (true) {
        int dsc = __hip_atomic_load(&g_desc[j], __ATOMIC_ACQUIRE, __HIP_MEMORY_SCOPE_AGENT);
        int st = dsc >> 28;
        if (st == 2)      { run += dsc & 0x0FFFFFFF; break; }
        else if (st == 1) { run += dsc & 0x0FFFFFFF; --j; }
        else              { __builtin_amdgcn_s_sleep(1); }
      }
      __hip_atomic_store(&g_desc[bi], (2<<28)|(run + A), __ATOMIC_RELEASE, __HIP_MEMORY_SCOPE_AGENT);
      spfx = run;
    }
  }
  __syncthreads();
  int off = spfx + sd[t] - v;             // global exclusive
  if (i < NC) {
    g_offs[i] = off;
    g_cur[i]  = off;
    if (i == NC-1) g_offs[NC] = off + v;  // total valid count
  }
}

// ---- 4) fill cell-sorted lists, wave-collapsed cursor bumps
__global__ void k_fill() {
  int p = blockIdx.x*256 + threadIdx.x;   // grid exact
  int code = g_code[p];
  int lane = threadIdx.x & 63;
  int prev = __shfl_up(code, 1);
  bool leader = (lane == 0) || (code != prev);
  unsigned long long m = __ballot(leader);
  unsigned long long mask_le = (lane==63) ? ~0ULL : ((1ULL << (lane+1)) - 1ULL);
  int leaderLane = 63 - __clzll(m & mask_le);
  int pos0 = 0;
  if (leader && code >= 0) {
    unsigned long long above = (lane < 63) ? (m >> (lane+1)) : 0ULL;
    int len = above ? __ffsll(above) : (64 - lane);
    pos0 = atomicAdd(&g_cur[code], len);
  }
  pos0 = __shfl(pos0, leaderLane);
  if (code >= 0) {
    int pos = pos0 + (lane - leaderLane);
    g_plist[pos] = p;
    g_clist[pos] = code;
  }
}

// ---- 5) gather: slot = SUB sorted points; prefetch everything, then collapse.
__device__ __forceinline__ void flush_run(float* __restrict__ out, int c, int c4,
                                          int s0, int s1,
                                          float ax, float ay, float az, float aw) {
  int o0 = g_offs[c], o1 = g_offs[c+1];
  int b = c / NCELL;
  int xy = c - b*NCELL;
  float* dst = out + (size_t)(b*C_ + c4*4)*NCELL + xy;
  if (o0 >= s0 && o1 <= s1) {             // exclusive owner -> plain stores
    dst[0]       = ax;
    dst[NCELL]   = ay;
    dst[2*NCELL] = az;
    dst[3*NCELL] = aw;
  } else {
    atomicAdd(dst,         ax);
    atomicAdd(dst+NCELL,   ay);
    atomicAdd(dst+2*NCELL, az);
    atomicAdd(dst+3*NCELL, aw);
  }
}

__global__ void __launch_bounds__(320) k_gather(const float* __restrict__ feats,
                                                float* __restrict__ out) {
  int T = g_offs[NC];
  int nslots = (T + SUB - 1) / SUB;
  int c4 = threadIdx.x % 20;
  int slotInBlk = threadIdx.x / 20;       // 0..15
  const float4* f4 = (const float4*)feats;

  for (int ss = blockIdx.x*16 + slotInBlk; ss < nslots; ss += gridDim.x*16) {
    int s0 = ss*SUB;
    if (T - s0 >= SUB) {
      // full slot: batch-prefetch lists and all 16 feats vectors (max MLP)
      int c[SUB], pl[SUB];
      const int4* cl4 = (const int4*)(g_clist + s0);
      const int4* pl4 = (const int4*)(g_plist + s0);
      #pragma unroll
      for (int k=0;k<SUB/4;++k) {
        int4 a = cl4[k]; c[4*k]=a.x; c[4*k+1]=a.y; c[4*k+2]=a.z; c[4*k+3]=a.w;
        int4 b = pl4[k]; pl[4*k]=b.x; pl[4*k+1]=b.y; pl[4*k+2]=b.z; pl[4*k+3]=b.w;
      }
      float4 v[SUB];
      #pragma unroll
      for (int k=0;k<SUB;++k) v[k] = f4[(size_t)pl[k]*20 + c4];
      int cur = c[0];
      float ax=v[0].x, ay=v[0].y, az=v[0].z, aw=v[0].w;
      #pragma unroll
      for (int k=1;k<SUB;++k) {
        if (c[k] != cur) {
          flush_run(out, cur, c4, s0, s0+SUB, ax, ay, az, aw);
          cur = c[k]; ax=v[k].x; ay=v[k].y; az=v[k].z; aw=v[k].w;
        } else {
          ax+=v[k].x; ay+=v[k].y; az+=v[k].z; aw+=v[k].w;
        }
      }
      flush_run(out, cur, c4, s0, s0+SUB, ax, ay, az, aw);
    } else {
      // tail slot (rare): guarded serial loop
      int cur = g_clist[s0];
      float ax=0.f, ay=0.f, az=0.f, aw=0.f;
      for (int j = s0; j < T; ++j) {
        int cc = g_clist[j];
        if (cc != cur) {
          flush_run(out, cur, c4, s0, T, ax, ay, az, aw);
          cur = cc; ax=ay=az=aw=0.f;
        }
        float4 vv = f4[(size_t)g_plist[j]*20 + c4];
        ax+=vv.x; ay+=vv.y; az+=vv.z; aw+=vv.w;
      }
      flush_run(out, cur, c4, s0, T, ax, ay, az, aw);
    }
  }
}

extern "C" void kernel_launch(void* const* d_in, const int* in_sizes, int n_in,
                              void* d_out, int out_size, void* d_ws, size_t ws_size,
                              hipStream_t stream) {
  const float* feats  = (const float*)d_in[0];
  const float* itrans = (const float*)d_in[1];
  const float* iscale = (const float*)d_in[2];
  const float* l2i    = (const float*)d_in[3];
  float* out = (float*)d_out;

  k_prep<<<NBLK, 256, 0, stream>>>(l2i);                       // 254 blocks
  k_geomz<<<NPTS/256, 256, 0, stream>>>(itrans, iscale, out);  // 7,788 blocks
  k_scan<<<NBLK, 1024, 0, stream>>>();                         // 254 blocks (all resident)
  k_fill<<<NPTS/256, 256, 0, stream>>>();                      // 7,788 blocks
  k_gather<<<704, 320, 0, stream>>>(feats, out);               // 704 blocks
}